// Round 1
// baseline (4094.228 us; speedup 1.0000x reference)
//
#include <hip/hip_runtime.h>
#include <hip/hip_bf16.h>
#include <math.h>

// MitosisDecoder: depth-4 binary GRU tree decoder.
// H=1024, B=64, V+1=32001, 31 nodes total (perfect heap, children 2i+1/2i+2).
// d_out = prod[31][64][32001] f32 (log_softmax per node, masked by validity).

constexpr int Hh  = 1024;
constexpr int Bb  = 64;
constexpr int V1  = 32001;

__device__ __forceinline__ float sigm(float x) { return 1.0f / (1.0f + expf(-x)); }

// ---------------- valid flags (heap propagate) ----------------
__global__ void compute_valid(const int* __restrict__ null_rand, int* __restrict__ valid) {
    if (threadIdx.x == 0 && blockIdx.x == 0) {
        valid[0] = (null_rand[0] != 0) ? 1 : 0;
        for (int i = 1; i < 31; i++)
            valid[i] = (valid[(i - 1) / 2] && (null_rand[i] != 0)) ? 1 : 0;
    }
}

// ---------------- simple copies / zero ----------------
__global__ void copy_f4(const float4* __restrict__ src, float4* __restrict__ dst, long n4) {
    long i = (long)blockIdx.x * blockDim.x + threadIdx.x;
    if (i < n4) dst[i] = src[i];
}
__global__ void zero_buf(float* __restrict__ p, long n) {
    long i = (long)blockIdx.x * blockDim.x + threadIdx.x;
    if (i < n) p[i] = 0.0f;
}

// ---------------- argmax over a row of V1 (first-index tie-break) ----------------
__global__ __launch_bounds__(256) void argmax_rows(const float* __restrict__ P,
                                                   int* __restrict__ word) {
    const int row = blockIdx.x;
    const float* p = P + (long)row * V1;
    const int t = threadIdx.x;
    float best = -INFINITY; int bidx = V1;
    for (int i = t; i < V1; i += 256) {
        float v = p[i];
        if (v > best) { best = v; bidx = i; }   // ascending i => first occurrence kept
    }
    __shared__ float sv[256]; __shared__ int si[256];
    sv[t] = best; si[t] = bidx; __syncthreads();
    for (int s = 128; s > 0; s >>= 1) {
        if (t < s) {
            float v2 = sv[t + s]; int i2 = si[t + s];
            if (v2 > sv[t] || (v2 == sv[t] && i2 < si[t])) { sv[t] = v2; si[t] = i2; }
        }
        __syncthreads();
    }
    if (t == 0) word[row] = si[0];
}

// ---------------- embedding gather ----------------
__global__ __launch_bounds__(256) void gather_emb(const float* __restrict__ emb,
                                                  const int* __restrict__ word,
                                                  float* __restrict__ xbuf) {
    const int r = blockIdx.x;
    const int t = threadIdx.x;                   // 256 threads * float4 = 1024 floats
    const float4* src = (const float4*)(emb + (long)word[r] * Hh);
    float4* dst = (float4*)(xbuf + (long)r * Hh);
    dst[t] = src[t];
}

// ---------------- fp32 GEMM: C[M,N] = A[M,K] * W[N,K]^T + bias[N] ----------------
// M multiple of 64 (grid.y = M/64); N-edge guarded. K multiple of 16.
__global__ __launch_bounds__(256) void gemm_nt_bias(const float* __restrict__ A,
                                                    const float* __restrict__ W,
                                                    const float* __restrict__ bias,
                                                    float* __restrict__ C,
                                                    int N, int K, long ldc) {
    __shared__ float As[16][65];
    __shared__ float Ws[16][65];
    const int bm = blockIdx.y * 64;
    const int bn = blockIdx.x * 64;
    const int tid = threadIdx.x;
    const int tx = tid & 15, ty = tid >> 4;
    const int lr = tid >> 2;          // 0..63
    const int lk = (tid & 3) * 4;     // 0,4,8,12
    float acc[4][4] = {};
    for (int k0 = 0; k0 < K; k0 += 16) {
        float4 av = *(const float4*)(A + (long)(bm + lr) * K + k0 + lk);
        float4 wv = make_float4(0.f, 0.f, 0.f, 0.f);
        const int wn = bn + lr;
        if (wn < N) wv = *(const float4*)(W + (long)wn * K + k0 + lk);
        As[lk + 0][lr] = av.x; As[lk + 1][lr] = av.y; As[lk + 2][lr] = av.z; As[lk + 3][lr] = av.w;
        Ws[lk + 0][lr] = wv.x; Ws[lk + 1][lr] = wv.y; Ws[lk + 2][lr] = wv.z; Ws[lk + 3][lr] = wv.w;
        __syncthreads();
        #pragma unroll
        for (int kk = 0; kk < 16; kk++) {
            float a[4], w[4];
            #pragma unroll
            for (int i = 0; i < 4; i++) a[i] = As[kk][ty * 4 + i];
            #pragma unroll
            for (int j = 0; j < 4; j++) w[j] = Ws[kk][tx * 4 + j];
            #pragma unroll
            for (int i = 0; i < 4; i++)
                #pragma unroll
                for (int j = 0; j < 4; j++)
                    acc[i][j] += a[i] * w[j];
        }
        __syncthreads();
    }
    #pragma unroll
    for (int i = 0; i < 4; i++) {
        #pragma unroll
        for (int j = 0; j < 4; j++) {
            int n = bn + tx * 4 + j;
            if (n < N) C[(long)(bm + ty * 4 + i) * ldc + n] = acc[i][j] + bias[n];
        }
    }
}

// ---------------- GRU gate fusion (both children) ----------------
// row r = p*B+b of level k; writes hl -> child (2p), hr -> child (2p+1) of level k+1.
__global__ __launch_bounds__(256) void gru_gates(const float* __restrict__ gil,
                                                 const float* __restrict__ ghl,
                                                 const float* __restrict__ gir,
                                                 const float* __restrict__ ghr,
                                                 const float* __restrict__ hprev,
                                                 float* __restrict__ hchild,
                                                 int rows) {
    long idx = (long)blockIdx.x * 256 + threadIdx.x;
    if (idx >= (long)rows * Hh) return;
    const int r = (int)(idx / Hh), c = (int)(idx % Hh);
    const int p = r / Bb, b = r % Bb;
    const float h = hprev[(long)r * Hh + c];
    const long g = (long)r * 3072;
    {   // left
        float ir = gil[g + c], iz = gil[g + Hh + c], in = gil[g + 2 * Hh + c];
        float hr = ghl[g + c], hz = ghl[g + Hh + c], hn = ghl[g + 2 * Hh + c];
        float rg = sigm(ir + hr), z = sigm(iz + hz);
        float n = tanhf(in + rg * hn);
        hchild[((long)(2 * p) * Bb + b) * Hh + c] = (1.0f - z) * n + z * h;
    }
    {   // right
        float ir = gir[g + c], iz = gir[g + Hh + c], in = gir[g + 2 * Hh + c];
        float hr = ghr[g + c], hz = ghr[g + Hh + c], hn = ghr[g + 2 * Hh + c];
        float rg = sigm(ir + hr), z = sigm(iz + hz);
        float n = tanhf(in + rg * hn);
        hchild[((long)(2 * p + 1) * Bb + b) * Hh + c] = (1.0f - z) * n + z * h;
    }
}

// ---------------- in-place log_softmax + eager validity mask ----------------
__global__ __launch_bounds__(256) void logsoftmax_mask(float* __restrict__ P,
                                                       const int* __restrict__ valid,
                                                       int nodeBase) {
    const int row = blockIdx.x;
    const int node = nodeBase + row / Bb;
    float* p = P + (long)row * V1;
    const int t = threadIdx.x;
    if (!valid[node]) {
        for (int i = t; i < V1; i += 256) p[i] = 0.0f;
        return;
    }
    __shared__ float red[256];
    float m = -INFINITY;
    for (int i = t; i < V1; i += 256) m = fmaxf(m, p[i]);
    red[t] = m; __syncthreads();
    for (int s = 128; s > 0; s >>= 1) { if (t < s) red[t] = fmaxf(red[t], red[t + s]); __syncthreads(); }
    m = red[0]; __syncthreads();
    float sum = 0.0f;
    for (int i = t; i < V1; i += 256) sum += expf(p[i] - m);
    red[t] = sum; __syncthreads();
    for (int s = 128; s > 0; s >>= 1) { if (t < s) red[t] += red[t + s]; __syncthreads(); }
    const float L = m + logf(red[0]);
    for (int i = t; i < V1; i += 256) p[i] = p[i] - L;
}

extern "C" void kernel_launch(void* const* d_in, const int* in_sizes, int n_in,
                              void* d_out, int out_size, void* d_ws, size_t ws_size,
                              hipStream_t stream) {
    const float* encoding = (const float*)d_in[0];
    const float* emb      = (const float*)d_in[1];
    const float* Wl_ih    = (const float*)d_in[2];
    const float* Wl_hh    = (const float*)d_in[3];
    const float* bl_ih    = (const float*)d_in[4];
    const float* bl_hh    = (const float*)d_in[5];
    const float* Wr_ih    = (const float*)d_in[6];
    const float* Wr_hh    = (const float*)d_in[7];
    const float* br_ih    = (const float*)d_in[8];
    const float* br_hh    = (const float*)d_in[9];
    const float* Wout     = (const float*)d_in[10];
    const float* bout     = (const float*)d_in[11];
    const int*   null_rand= (const int*)d_in[12];
    float* out = (float*)d_out;

    // workspace layout (~35.4 MB total)
    float* hid  = (float*)d_ws;                   // 31*64*1024
    float* xbuf = hid  + 31L * Bb * Hh;           // 512*1024
    float* gil  = xbuf + 512L * Hh;               // 512*3072 each
    float* ghl  = gil  + 512L * 3072;
    float* gir  = ghl  + 512L * 3072;
    float* ghr  = gir  + 512L * 3072;
    int*   word = (int*)(ghr + 512L * 3072);      // 512
    int*   valid= word + 512;                     // 31

    compute_valid<<<1, 64, 0, stream>>>(null_rand, valid);

    // hid[node0] = encoding  (64*1024 floats = 16384 float4)
    copy_f4<<<64, 256, 0, stream>>>((const float4*)encoding, (float4*)hid, 16384L);

    // prod[node0] = zeros
    const long n0 = (long)Bb * V1;
    zero_buf<<<(int)((n0 + 255) / 256), 256, 0, stream>>>(out, n0);

    for (int k = 0; k < 4; k++) {
        const int  nl   = 1 << k;
        const int  rows = nl * Bb;                 // 64..512
        const long lbk  = (1L << k) - 1;           // level-k node base
        const long lbc  = (1L << (k + 1)) - 1;     // child level base

        argmax_rows<<<rows, 256, 0, stream>>>(out + lbk * Bb * V1, word);
        gather_emb<<<rows, 256, 0, stream>>>(emb, word, xbuf);

        dim3 gg(48, rows / 64);                    // N=3072 tiles
        const float* hk = hid + lbk * Bb * Hh;
        gemm_nt_bias<<<gg, 256, 0, stream>>>(xbuf, Wl_ih, bl_ih, gil, 3072, 1024, 3072);
        gemm_nt_bias<<<gg, 256, 0, stream>>>(hk,   Wl_hh, bl_hh, ghl, 3072, 1024, 3072);
        gemm_nt_bias<<<gg, 256, 0, stream>>>(xbuf, Wr_ih, br_ih, gir, 3072, 1024, 3072);
        gemm_nt_bias<<<gg, 256, 0, stream>>>(hk,   Wr_hh, br_hh, ghr, 3072, 1024, 3072);

        const long tot = (long)rows * Hh;
        gru_gates<<<(int)((tot + 255) / 256), 256, 0, stream>>>(
            gil, ghl, gir, ghr, hk, hid + lbc * Bb * Hh, rows);

        dim3 gp((V1 + 63) / 64, 2 * rows / 64);    // 501 x (2..16)
        gemm_nt_bias<<<gp, 256, 0, stream>>>(hid + lbc * Bb * Hh, Wout, bout,
                                             out + lbc * Bb * V1, V1, 1024, V1);

        logsoftmax_mask<<<2 * rows, 256, 0, stream>>>(out + lbc * Bb * V1, valid, (int)lbc);
    }
}

// Round 2
// 1254.076 us; speedup vs baseline: 3.2647x; 3.2647x over previous
//
#include <hip/hip_runtime.h>
#include <math.h>

// MitosisDecoder: depth-4 binary GRU tree decoder.
// H=1024, B=64, V+1=32001, 31 nodes (heap). out = log_softmax per node, masked.
// Fast path: bf16x3 split-precision MFMA GEMMs (Ah*Bh + Ah*Bl + Al*Bh, fp32 acc).

constexpr int Hh  = 1024;
constexpr int Bb  = 64;
constexpr int V1  = 32001;
constexpr long NH = (long)Bb * Hh;     // elems per node of hidden

typedef __bf16 bf16x8 __attribute__((ext_vector_type(8)));
typedef float  f32x4  __attribute__((ext_vector_type(4)));

__device__ __forceinline__ float sigm(float x) { return 1.0f / (1.0f + expf(-x)); }

__device__ __forceinline__ unsigned short f2bf(float x) {
    unsigned int u = __builtin_bit_cast(unsigned int, x);
    u = (u + 0x7fffu + ((u >> 16) & 1u)) >> 16;
    return (unsigned short)u;
}
__device__ __forceinline__ float bf2f(unsigned short b) {
    unsigned int u = ((unsigned int)b) << 16;
    return __builtin_bit_cast(float, u);
}
__device__ __forceinline__ void dec2(float v, unsigned short& hi, unsigned short& lo) {
    hi = f2bf(v);
    lo = f2bf(v - bf2f(hi));
}
__device__ __forceinline__ void gload16(const unsigned short* g, unsigned short* l) {
    __builtin_amdgcn_global_load_lds((__attribute__((address_space(1))) void*)g,
                                     (__attribute__((address_space(3))) void*)l,
                                     16, 0, 0);
}

// ---------------- valid flags (heap propagate) ----------------
__global__ void compute_valid(const int* __restrict__ null_rand, int* __restrict__ valid) {
    if (threadIdx.x == 0 && blockIdx.x == 0) {
        valid[0] = (null_rand[0] != 0) ? 1 : 0;
        for (int i = 1; i < 31; i++)
            valid[i] = (valid[(i - 1) / 2] && (null_rand[i] != 0)) ? 1 : 0;
    }
}

// ---------------- simple copies / zero ----------------
__global__ void copy_f4(const float4* __restrict__ src, float4* __restrict__ dst, long n4) {
    long i = (long)blockIdx.x * blockDim.x + threadIdx.x;
    if (i < n4) dst[i] = src[i];
}
__global__ void zero_buf(float* __restrict__ p, long n) {
    long i = (long)blockIdx.x * blockDim.x + threadIdx.x;
    if (i < n) p[i] = 0.0f;
}

// copy encoding -> hid f32 + decomposed hi/lo
__global__ __launch_bounds__(256) void copy_dec(const float* __restrict__ src,
                                                float* __restrict__ dst,
                                                unsigned short* __restrict__ dstH,
                                                unsigned short* __restrict__ dstL,
                                                long n4) {
    long i = (long)blockIdx.x * blockDim.x + threadIdx.x;
    if (i >= n4) return;
    float4 v = ((const float4*)src)[i];
    ((float4*)dst)[i] = v;
    ushort4 h, l;
    dec2(v.x, h.x, l.x); dec2(v.y, h.y, l.y); dec2(v.z, h.z, l.z); dec2(v.w, h.w, l.w);
    ((ushort4*)dstH)[i] = h;
    ((ushort4*)dstL)[i] = l;
}

// f32 array -> hi/lo bf16 arrays (grid-stride over float4s)
__global__ __launch_bounds__(256) void decompose_f32(const float* __restrict__ src,
                                                     unsigned short* __restrict__ hi,
                                                     unsigned short* __restrict__ lo,
                                                     long n4) {
    for (long i = (long)blockIdx.x * blockDim.x + threadIdx.x; i < n4;
         i += (long)gridDim.x * blockDim.x) {
        float4 v = ((const float4*)src)[i];
        ushort4 h, l;
        dec2(v.x, h.x, l.x); dec2(v.y, h.y, l.y); dec2(v.z, h.z, l.z); dec2(v.w, h.w, l.w);
        ((ushort4*)hi)[i] = h;
        ((ushort4*)lo)[i] = l;
    }
}

__global__ __launch_bounds__(256) void cat_bias(const float* __restrict__ a,
                                                const float* __restrict__ b,
                                                float* __restrict__ dst) {
    int i = blockIdx.x * 256 + threadIdx.x;
    if (i < 3072) { dst[i] = a[i]; dst[3072 + i] = b[i]; }
}

// ---------------- argmax over a row of V1 (first-index tie-break) ----------------
__global__ __launch_bounds__(256) void argmax_rows(const float* __restrict__ P,
                                                   int* __restrict__ word) {
    const int row = blockIdx.x;
    const float* p = P + (long)row * V1;
    const int t = threadIdx.x;
    float best = -INFINITY; int bidx = V1;
    for (int i = t; i < V1; i += 256) {
        float v = p[i];
        if (v > best) { best = v; bidx = i; }
    }
    __shared__ float sv[256]; __shared__ int si[256];
    sv[t] = best; si[t] = bidx; __syncthreads();
    for (int s = 128; s > 0; s >>= 1) {
        if (t < s) {
            float v2 = sv[t + s]; int i2 = si[t + s];
            if (v2 > sv[t] || (v2 == sv[t] && i2 < si[t])) { sv[t] = v2; si[t] = i2; }
        }
        __syncthreads();
    }
    if (t == 0) word[row] = si[0];
}

// ---------------- embedding gather (+ optional decompose for fast path) ----------------
__global__ __launch_bounds__(256) void gather_emb(const float* __restrict__ emb,
                                                  const int* __restrict__ word,
                                                  float* __restrict__ xbuf) {
    const int r = blockIdx.x;
    const int t = threadIdx.x;
    const float4* src = (const float4*)(emb + (long)word[r] * Hh);
    float4* dst = (float4*)(xbuf + (long)r * Hh);
    dst[t] = src[t];
}
__global__ __launch_bounds__(256) void gather_emb_dec(const float* __restrict__ emb,
                                                      const int* __restrict__ word,
                                                      unsigned short* __restrict__ xH,
                                                      unsigned short* __restrict__ xL) {
    const int r = blockIdx.x;
    const int t = threadIdx.x;
    float4 v = ((const float4*)(emb + (long)word[r] * Hh))[t];
    ushort4 h, l;
    dec2(v.x, h.x, l.x); dec2(v.y, h.y, l.y); dec2(v.z, h.z, l.z); dec2(v.w, h.w, l.w);
    ((ushort4*)(xH + (long)r * Hh))[t] = h;
    ((ushort4*)(xL + (long)r * Hh))[t] = l;
}

// ---------------- bf16x3 MFMA GEMM: C[M,N] = A[M,K] * B[N,K]^T + bias ----------------
// A,B given as hi/lo bf16 pairs. 128x128 tile, BK=32, 4 waves (2x2 of 64x64).
__global__ __launch_bounds__(256) void gemm3_nt(
    const unsigned short* __restrict__ AH, const unsigned short* __restrict__ AL,
    const unsigned short* __restrict__ BH, const unsigned short* __restrict__ BL,
    const float* __restrict__ bias, float* __restrict__ C,
    int M, int N, int K, long ldc)
{
    __shared__ __align__(16) unsigned short sm[4 * 4096];   // 32 KiB
    unsigned short* sAH = sm;
    unsigned short* sAL = sm + 4096;
    unsigned short* sBH = sm + 8192;
    unsigned short* sBL = sm + 12288;

    const int tid  = threadIdx.x;
    const int lane = tid & 63;
    const int wid  = tid >> 6;
    const int bm = blockIdx.y * 128, bn = blockIdx.x * 128;
    const int wr = (wid >> 1) * 64,  wc = (wid & 1) * 64;

    // staging: thread -> (row, kblock); LDS tile is [128][32] bf16, lane-linear
    const int sr = tid >> 2;             // 0..63
    const int sk = (tid & 3) * 8;        // 0,8,16,24 (elems)
    const int ar0 = min(bm + sr,      M - 1);
    const int ar1 = min(bm + 64 + sr, M - 1);
    const int br0 = min(bn + sr,      N - 1);
    const int br1 = min(bn + 64 + sr, N - 1);
    const unsigned short* gA0h = AH + (long)ar0 * K + sk;
    const unsigned short* gA1h = AH + (long)ar1 * K + sk;
    const unsigned short* gA0l = AL + (long)ar0 * K + sk;
    const unsigned short* gA1l = AL + (long)ar1 * K + sk;
    const unsigned short* gB0h = BH + (long)br0 * K + sk;
    const unsigned short* gB1h = BH + (long)br1 * K + sk;
    const unsigned short* gB0l = BL + (long)br0 * K + sk;
    const unsigned short* gB1l = BL + (long)br1 * K + sk;
    unsigned short* lA0h = sAH + tid * 8;  unsigned short* lA1h = sAH + 2048 + tid * 8;
    unsigned short* lA0l = sAL + tid * 8;  unsigned short* lA1l = sAL + 2048 + tid * 8;
    unsigned short* lB0h = sBH + tid * 8;  unsigned short* lB1h = sBH + 2048 + tid * 8;
    unsigned short* lB0l = sBL + tid * 8;  unsigned short* lB1l = sBL + 2048 + tid * 8;

    f32x4 acc[4][4] = {};
    const int arow = wr + (lane & 15);
    const int brow = wc + (lane & 15);
    const int koff = (lane >> 4) * 16;   // byte offset within 64B LDS row

    for (int k0 = 0; k0 < K; k0 += 32) {
        gload16(gA0h + k0, lA0h);  gload16(gA1h + k0, lA1h);
        gload16(gA0l + k0, lA0l);  gload16(gA1l + k0, lA1l);
        gload16(gB0h + k0, lB0h);  gload16(gB1h + k0, lB1h);
        gload16(gB0l + k0, lB0l);  gload16(gB1l + k0, lB1l);
        __syncthreads();

        bf16x8 ah[4], al[4], bh[4], bl[4];
        #pragma unroll
        for (int m = 0; m < 4; m++) {
            ah[m] = *(const bf16x8*)((const char*)sAH + (arow + m * 16) * 64 + koff);
            al[m] = *(const bf16x8*)((const char*)sAL + (arow + m * 16) * 64 + koff);
        }
        #pragma unroll
        for (int n = 0; n < 4; n++) {
            bh[n] = *(const bf16x8*)((const char*)sBH + (brow + n * 16) * 64 + koff);
            bl[n] = *(const bf16x8*)((const char*)sBL + (brow + n * 16) * 64 + koff);
        }
        #pragma unroll
        for (int m = 0; m < 4; m++) {
            #pragma unroll
            for (int n = 0; n < 4; n++) {
                acc[m][n] = __builtin_amdgcn_mfma_f32_16x16x32_bf16(ah[m], bh[n], acc[m][n], 0, 0, 0);
                acc[m][n] = __builtin_amdgcn_mfma_f32_16x16x32_bf16(ah[m], bl[n], acc[m][n], 0, 0, 0);
                acc[m][n] = __builtin_amdgcn_mfma_f32_16x16x32_bf16(al[m], bh[n], acc[m][n], 0, 0, 0);
            }
        }
        __syncthreads();
    }

    const int r0 = (lane >> 4) * 4;      // C/D: col=lane&15, row=(lane>>4)*4+j  [m89/m91]
    #pragma unroll
    for (int n = 0; n < 4; n++) {
        const int gcol = bn + wc + n * 16 + (lane & 15);
        if (gcol >= N) continue;
        const float bv = bias[gcol];
        #pragma unroll
        for (int m = 0; m < 4; m++) {
            #pragma unroll
            for (int j = 0; j < 4; j++) {
                const int grow = bm + wr + m * 16 + r0 + j;
                if (grow < M) C[(long)grow * ldc + gcol] = acc[m][n][j] + bv;
            }
        }
    }
}

// ---------------- fp32 GEMM (fallback path) ----------------
__global__ __launch_bounds__(256) void gemm_nt_bias(const float* __restrict__ A,
                                                    const float* __restrict__ W,
                                                    const float* __restrict__ bias,
                                                    float* __restrict__ C,
                                                    int N, int K, long ldc) {
    __shared__ float As[16][65];
    __shared__ float Ws[16][65];
    const int bm = blockIdx.y * 64;
    const int bn = blockIdx.x * 64;
    const int tid = threadIdx.x;
    const int tx = tid & 15, ty = tid >> 4;
    const int lr = tid >> 2;
    const int lk = (tid & 3) * 4;
    float acc[4][4] = {};
    for (int k0 = 0; k0 < K; k0 += 16) {
        float4 av = *(const float4*)(A + (long)(bm + lr) * K + k0 + lk);
        float4 wv = make_float4(0.f, 0.f, 0.f, 0.f);
        const int wn = bn + lr;
        if (wn < N) wv = *(const float4*)(W + (long)wn * K + k0 + lk);
        As[lk + 0][lr] = av.x; As[lk + 1][lr] = av.y; As[lk + 2][lr] = av.z; As[lk + 3][lr] = av.w;
        Ws[lk + 0][lr] = wv.x; Ws[lk + 1][lr] = wv.y; Ws[lk + 2][lr] = wv.z; Ws[lk + 3][lr] = wv.w;
        __syncthreads();
        #pragma unroll
        for (int kk = 0; kk < 16; kk++) {
            float a[4], w[4];
            #pragma unroll
            for (int i = 0; i < 4; i++) a[i] = As[kk][ty * 4 + i];
            #pragma unroll
            for (int j = 0; j < 4; j++) w[j] = Ws[kk][tx * 4 + j];
            #pragma unroll
            for (int i = 0; i < 4; i++)
                #pragma unroll
                for (int j = 0; j < 4; j++)
                    acc[i][j] += a[i] * w[j];
        }
        __syncthreads();
    }
    #pragma unroll
    for (int i = 0; i < 4; i++)
        #pragma unroll
        for (int j = 0; j < 4; j++) {
            int n = bn + tx * 4 + j;
            if (n < N) C[(long)(bm + ty * 4 + i) * ldc + n] = acc[i][j] + bias[n];
        }
}

// ---------------- GRU gate fusion ----------------
// fast path: cat gates [rows][6144]; writes child h f32 + decomposed bf16 hi/lo
__global__ __launch_bounds__(256) void gru_gates_dec(const float* __restrict__ gi,
                                                     const float* __restrict__ gh,
                                                     const float* __restrict__ hprev,
                                                     float* __restrict__ hc,
                                                     unsigned short* __restrict__ hcH,
                                                     unsigned short* __restrict__ hcL,
                                                     int rows) {
    long idx = (long)blockIdx.x * 256 + threadIdx.x;
    if (idx >= (long)rows * Hh) return;
    const int r = (int)(idx / Hh), c = (int)(idx % Hh);
    const int p = r / Bb, b = r % Bb;
    const float h = hprev[idx];
    const long g = (long)r * 6144;
    {   // left (cols 0..3071)
        float ir = gi[g + c], iz = gi[g + 1024 + c], in = gi[g + 2048 + c];
        float hr = gh[g + c], hz = gh[g + 1024 + c], hn = gh[g + 2048 + c];
        float rg = sigm(ir + hr), z = sigm(iz + hz);
        float nn = tanhf(in + rg * hn);
        float hv = (1.0f - z) * nn + z * h;
        long o = ((long)(2 * p) * Bb + b) * Hh + c;
        hc[o] = hv; dec2(hv, hcH[o], hcL[o]);
    }
    {   // right (cols 3072..6143)
        float ir = gi[g + 3072 + c], iz = gi[g + 4096 + c], in = gi[g + 5120 + c];
        float hr = gh[g + 3072 + c], hz = gh[g + 4096 + c], hn = gh[g + 5120 + c];
        float rg = sigm(ir + hr), z = sigm(iz + hz);
        float nn = tanhf(in + rg * hn);
        float hv = (1.0f - z) * nn + z * h;
        long o = ((long)(2 * p + 1) * Bb + b) * Hh + c;
        hc[o] = hv; dec2(hv, hcH[o], hcL[o]);
    }
}

// fallback-path gates (separate l/r buffers)
__global__ __launch_bounds__(256) void gru_gates_f32(const float* __restrict__ gil,
                                                     const float* __restrict__ ghl,
                                                     const float* __restrict__ gir,
                                                     const float* __restrict__ ghr,
                                                     const float* __restrict__ hprev,
                                                     float* __restrict__ hchild,
                                                     int rows) {
    long idx = (long)blockIdx.x * 256 + threadIdx.x;
    if (idx >= (long)rows * Hh) return;
    const int r = (int)(idx / Hh), c = (int)(idx % Hh);
    const int p = r / Bb, b = r % Bb;
    const float h = hprev[(long)r * Hh + c];
    const long g = (long)r * 3072;
    {
        float ir = gil[g + c], iz = gil[g + Hh + c], in = gil[g + 2 * Hh + c];
        float hr = ghl[g + c], hz = ghl[g + Hh + c], hn = ghl[g + 2 * Hh + c];
        float rg = sigm(ir + hr), z = sigm(iz + hz);
        float n = tanhf(in + rg * hn);
        hchild[((long)(2 * p) * Bb + b) * Hh + c] = (1.0f - z) * n + z * h;
    }
    {
        float ir = gir[g + c], iz = gir[g + Hh + c], in = gir[g + 2 * Hh + c];
        float hr = ghr[g + c], hz = ghr[g + Hh + c], hn = ghr[g + 2 * Hh + c];
        float rg = sigm(ir + hr), z = sigm(iz + hz);
        float n = tanhf(in + rg * hn);
        hchild[((long)(2 * p + 1) * Bb + b) * Hh + c] = (1.0f - z) * n + z * h;
    }
}

// ---------------- in-place log_softmax + eager validity mask ----------------
__global__ __launch_bounds__(256) void logsoftmax_mask(float* __restrict__ P,
                                                       const int* __restrict__ valid,
                                                       int nodeBase) {
    const int row = blockIdx.x;
    const int node = nodeBase + row / Bb;
    float* p = P + (long)row * V1;
    const int t = threadIdx.x;
    if (!valid[node]) {
        for (int i = t; i < V1; i += 256) p[i] = 0.0f;
        return;
    }
    __shared__ float red[256];
    float m = -INFINITY;
    for (int i = t; i < V1; i += 256) m = fmaxf(m, p[i]);
    red[t] = m; __syncthreads();
    for (int s = 128; s > 0; s >>= 1) { if (t < s) red[t] = fmaxf(red[t], red[t + s]); __syncthreads(); }
    m = red[0]; __syncthreads();
    float sum = 0.0f;
    for (int i = t; i < V1; i += 256) sum += expf(p[i] - m);
    red[t] = sum; __syncthreads();
    for (int s = 128; s > 0; s >>= 1) { if (t < s) red[t] += red[t + s]; __syncthreads(); }
    const float L = m + logf(red[0]);
    for (int i = t; i < V1; i += 256) p[i] = p[i] - L;
}

extern "C" void kernel_launch(void* const* d_in, const int* in_sizes, int n_in,
                              void* d_out, int out_size, void* d_ws, size_t ws_size,
                              hipStream_t stream) {
    const float* encoding = (const float*)d_in[0];
    const float* emb      = (const float*)d_in[1];
    const float* Wl_ih    = (const float*)d_in[2];
    const float* Wl_hh    = (const float*)d_in[3];
    const float* bl_ih    = (const float*)d_in[4];
    const float* bl_hh    = (const float*)d_in[5];
    const float* Wr_ih    = (const float*)d_in[6];
    const float* Wr_hh    = (const float*)d_in[7];
    const float* br_ih    = (const float*)d_in[8];
    const float* br_hh    = (const float*)d_in[9];
    const float* Wout     = (const float*)d_in[10];
    const float* bout     = (const float*)d_in[11];
    const int*   null_rand= (const int*)d_in[12];
    float* out = (float*)d_out;

    // ---- fast-path workspace layout (~225 MB) ----
    char* w = (char*)d_ws;
    size_t off = 0;
    auto take = [&](size_t bytes) -> char* {
        char* p = w + off;
        off += (bytes + 255) & ~(size_t)255;
        return p;
    };
    float*          hid   = (float*)take(2031616L * 4);          // 31*64*1024 f32
    unsigned short* hidH  = (unsigned short*)take(2031616L * 2);
    unsigned short* hidL  = (unsigned short*)take(2031616L * 2);
    unsigned short* xH    = (unsigned short*)take(524288L * 2);  // 512*1024
    unsigned short* xL    = (unsigned short*)take(524288L * 2);
    float*          gi    = (float*)take(3145728L * 4);          // 512*6144
    float*          gh    = (float*)take(3145728L * 4);
    unsigned short* WoutH = (unsigned short*)take(32769024L * 2);
    unsigned short* WoutL = (unsigned short*)take(32769024L * 2);
    unsigned short* WihH  = (unsigned short*)take(6291456L * 2); // 6144*1024
    unsigned short* WihL  = (unsigned short*)take(6291456L * 2);
    unsigned short* WhhH  = (unsigned short*)take(6291456L * 2);
    unsigned short* WhhL  = (unsigned short*)take(6291456L * 2);
    float*          bih   = (float*)take(6144L * 4);
    float*          bhh   = (float*)take(6144L * 4);
    int*            word  = (int*)take(512L * 4);
    int*            valid = (int*)take(31L * 4);
    const bool fast = (off <= ws_size);

    if (fast) {
        compute_valid<<<1, 64, 0, stream>>>(null_rand, valid);
        decompose_f32<<<2048, 256, 0, stream>>>(Wout,  WoutH, WoutL, 8192256L);
        decompose_f32<<<1024, 256, 0, stream>>>(Wl_ih, WihH,           WihL,           786432L);
        decompose_f32<<<1024, 256, 0, stream>>>(Wr_ih, WihH + 3145728, WihL + 3145728, 786432L);
        decompose_f32<<<1024, 256, 0, stream>>>(Wl_hh, WhhH,           WhhL,           786432L);
        decompose_f32<<<1024, 256, 0, stream>>>(Wr_hh, WhhH + 3145728, WhhL + 3145728, 786432L);
        cat_bias<<<12, 256, 0, stream>>>(bl_ih, br_ih, bih);
        cat_bias<<<12, 256, 0, stream>>>(bl_hh, br_hh, bhh);
        copy_dec<<<64, 256, 0, stream>>>(encoding, hid, hidH, hidL, 16384L);
        const long n0 = (long)Bb * V1;
        zero_buf<<<(int)((n0 + 255) / 256), 256, 0, stream>>>(out, n0);

        for (int k = 0; k < 4; k++) {
            const int  rows = (1 << k) * Bb;           // 64..512
            const long lbk  = (1L << k) - 1;
            const long lbc  = (1L << (k + 1)) - 1;

            argmax_rows<<<rows, 256, 0, stream>>>(out + lbk * Bb * V1, word);
            gather_emb_dec<<<rows, 256, 0, stream>>>(emb, word, xH, xL);

            dim3 gg(48, (rows + 127) / 128);
            gemm3_nt<<<gg, 256, 0, stream>>>(xH, xL, WihH, WihL, bih, gi,
                                             rows, 6144, 1024, 6144);
            gemm3_nt<<<gg, 256, 0, stream>>>(hidH + lbk * NH, hidL + lbk * NH,
                                             WhhH, WhhL, bhh, gh,
                                             rows, 6144, 1024, 6144);
            gru_gates_dec<<<rows * 4, 256, 0, stream>>>(gi, gh, hid + lbk * NH,
                                                        hid + lbc * NH,
                                                        hidH + lbc * NH, hidL + lbc * NH,
                                                        rows);
            dim3 gp((V1 + 127) / 128, (2 * rows + 127) / 128);
            gemm3_nt<<<gp, 256, 0, stream>>>(hidH + lbc * NH, hidL + lbc * NH,
                                             WoutH, WoutL, bout,
                                             out + lbc * Bb * V1,
                                             2 * rows, V1, 1024, V1);
            logsoftmax_mask<<<2 * rows, 256, 0, stream>>>(out + lbc * Bb * V1, valid, (int)lbc);
        }
        return;
    }

    // ---------------- fallback: round-1 fp32 path (~35 MB ws) ----------------
    float* f_hid  = (float*)d_ws;
    float* f_xbuf = f_hid  + 31L * Bb * Hh;
    float* f_gil  = f_xbuf + 512L * Hh;
    float* f_ghl  = f_gil  + 512L * 3072;
    float* f_gir  = f_ghl  + 512L * 3072;
    float* f_ghr  = f_gir  + 512L * 3072;
    int*   f_word = (int*)(f_ghr + 512L * 3072);
    int*   f_valid= f_word + 512;

    compute_valid<<<1, 64, 0, stream>>>(null_rand, f_valid);
    copy_f4<<<64, 256, 0, stream>>>((const float4*)encoding, (float4*)f_hid, 16384L);
    const long n0 = (long)Bb * V1;
    zero_buf<<<(int)((n0 + 255) / 256), 256, 0, stream>>>(out, n0);

    for (int k = 0; k < 4; k++) {
        const int  rows = (1 << k) * Bb;
        const long lbk  = (1L << k) - 1;
        const long lbc  = (1L << (k + 1)) - 1;

        argmax_rows<<<rows, 256, 0, stream>>>(out + lbk * Bb * V1, f_word);
        gather_emb<<<rows, 256, 0, stream>>>(emb, f_word, f_xbuf);

        dim3 gg(48, rows / 64);
        const float* hk = f_hid + lbk * NH;
        gemm_nt_bias<<<gg, 256, 0, stream>>>(f_xbuf, Wl_ih, bl_ih, f_gil, 3072, 1024, 3072);
        gemm_nt_bias<<<gg, 256, 0, stream>>>(hk,     Wl_hh, bl_hh, f_ghl, 3072, 1024, 3072);
        gemm_nt_bias<<<gg, 256, 0, stream>>>(f_xbuf, Wr_ih, br_ih, f_gir, 3072, 1024, 3072);
        gemm_nt_bias<<<gg, 256, 0, stream>>>(hk,     Wr_hh, br_hh, f_ghr, 3072, 1024, 3072);

        const long tot = (long)rows * Hh;
        gru_gates_f32<<<(int)((tot + 255) / 256), 256, 0, stream>>>(
            f_gil, f_ghl, f_gir, f_ghr, hk, f_hid + lbc * NH, rows);

        dim3 gp((V1 + 63) / 64, 2 * rows / 64);
        gemm_nt_bias<<<gp, 256, 0, stream>>>(f_hid + lbc * NH, Wout, bout,
                                             out + lbc * Bb * V1, V1, 1024, V1);
        logsoftmax_mask<<<2 * rows, 256, 0, stream>>>(out + lbc * Bb * V1, valid ? f_valid : f_valid, (int)lbc);
    }
}

// Round 3
// 196.853 us; speedup vs baseline: 20.7984x; 6.3706x over previous
//
#include <hip/hip_runtime.h>
#include <math.h>

// MitosisDecoder: depth-4 binary GRU tree decoder. H=1024, B=64, V+1=32001,
// 31 nodes (heap). out = log_softmax per node, masked by heap validity.
// Fast path: validity-pruned (compacted M) bf16x3 split-precision MFMA GEMMs.

constexpr int Hh  = 1024;
constexpr int Bb  = 64;
constexpr int V1  = 32001;
constexpr long NH = (long)Bb * Hh;

typedef __bf16 bf16x8 __attribute__((ext_vector_type(8)));
typedef float  f32x4  __attribute__((ext_vector_type(4)));

__device__ __forceinline__ float sigm(float x) { return 1.0f / (1.0f + expf(-x)); }

__device__ __forceinline__ unsigned short f2bf(float x) {
    unsigned int u = __builtin_bit_cast(unsigned int, x);
    u = (u + 0x7fffu + ((u >> 16) & 1u)) >> 16;
    return (unsigned short)u;
}
__device__ __forceinline__ float bf2f(unsigned short b) {
    unsigned int u = ((unsigned int)b) << 16;
    return __builtin_bit_cast(float, u);
}
__device__ __forceinline__ void dec2(float v, unsigned short& hi, unsigned short& lo) {
    hi = f2bf(v);
    lo = f2bf(v - bf2f(hi));
}
__device__ __forceinline__ void gload16(const unsigned short* g, unsigned short* l) {
    __builtin_amdgcn_global_load_lds((__attribute__((address_space(1))) void*)g,
                                     (__attribute__((address_space(3))) void*)l,
                                     16, 0, 0);
}

// ---------------- validity + compaction metadata (1 thread) ----------------
__global__ void build_meta(const int* __restrict__ null_rand, int* __restrict__ valid,
                           int* __restrict__ cntP, int* __restrict__ listP,
                           int* __restrict__ cntC, int* __restrict__ listC,
                           int* __restrict__ posC) {
    if (threadIdx.x != 0 || blockIdx.x != 0) return;
    valid[0] = (null_rand[0] != 0) ? 1 : 0;
    for (int i = 1; i < 31; i++)
        valid[i] = (valid[(i - 1) / 2] && (null_rand[i] != 0)) ? 1 : 0;
    for (int k = 0; k < 4; k++) {
        int np = 0;
        for (int p = 0; p < (1 << k); p++)
            if (valid[(1 << k) - 1 + p]) listP[k * 8 + np++] = p;
        cntP[k] = np;
        int nc = 0;
        for (int c = 0; c < (2 << k); c++) {
            if (valid[(2 << k) - 1 + c]) { posC[k * 16 + c] = nc; listC[k * 16 + nc] = c; nc++; }
            else posC[k * 16 + c] = -1;
        }
        cntC[k] = nc;
    }
}

__global__ void set_word0(int* __restrict__ word) {
    if (threadIdx.x < 64) word[threadIdx.x] = 0;
}

__global__ void copy_f4(const float4* __restrict__ src, float4* __restrict__ dst, long n4) {
    long i = (long)blockIdx.x * blockDim.x + threadIdx.x;
    if (i < n4) dst[i] = src[i];
}
__global__ void zero_buf(float* __restrict__ p, long n) {
    long i = (long)blockIdx.x * blockDim.x + threadIdx.x;
    if (i < n) p[i] = 0.0f;
}

// f32 -> hi/lo bf16 planes (grid-stride over float4)
__global__ __launch_bounds__(256) void decompose_f32(const float* __restrict__ src,
                                                     unsigned short* __restrict__ hi,
                                                     unsigned short* __restrict__ lo,
                                                     long n4) {
    for (long i = (long)blockIdx.x * blockDim.x + threadIdx.x; i < n4;
         i += (long)gridDim.x * blockDim.x) {
        float4 v = ((const float4*)src)[i];
        ushort4 h, l;
        dec2(v.x, h.x, l.x); dec2(v.y, h.y, l.y); dec2(v.z, h.z, l.z); dec2(v.w, h.w, l.w);
        ((ushort4*)hi)[i] = h;
        ((ushort4*)lo)[i] = l;
    }
}

__global__ __launch_bounds__(256) void cat_bias(const float* __restrict__ a,
                                                const float* __restrict__ b,
                                                float* __restrict__ dst) {
    int i = blockIdx.x * 256 + threadIdx.x;
    if (i < 3072) { dst[i] = a[i]; dst[3072 + i] = b[i]; }
}

// ---------------- gather: x = emb[word], h = hid[parent] -> compacted hi/lo ----------------
__global__ __launch_bounds__(256) void gather_pack(const float* __restrict__ emb,
                                                   const float* __restrict__ hidK,
                                                   const int* __restrict__ word,
                                                   const int* __restrict__ listPk,
                                                   const int* __restrict__ cntPk,
                                                   unsigned short* __restrict__ xH,
                                                   unsigned short* __restrict__ xL,
                                                   unsigned short* __restrict__ hH,
                                                   unsigned short* __restrict__ hL,
                                                   float* __restrict__ hbufF) {
    const int r = blockIdx.x;
    if (r >= cntPk[0] * 64) return;
    const int lp = listPk[r >> 6], b = r & 63;
    const int t = threadIdx.x;
    const int w = word[lp * 64 + b];
    float4 xv = ((const float4*)(emb + (long)w * Hh))[t];
    float4 hv = ((const float4*)(hidK + ((long)lp * 64 + b) * Hh))[t];
    ushort4 h4, l4;
    dec2(xv.x, h4.x, l4.x); dec2(xv.y, h4.y, l4.y); dec2(xv.z, h4.z, l4.z); dec2(xv.w, h4.w, l4.w);
    ((ushort4*)(xH + (long)r * Hh))[t] = h4;
    ((ushort4*)(xL + (long)r * Hh))[t] = l4;
    dec2(hv.x, h4.x, l4.x); dec2(hv.y, h4.y, l4.y); dec2(hv.z, h4.z, l4.z); dec2(hv.w, h4.w, l4.w);
    ((ushort4*)(hH + (long)r * Hh))[t] = h4;
    ((ushort4*)(hL + (long)r * Hh))[t] = l4;
    ((float4*)(hbufF + (long)r * Hh))[t] = hv;
}

// ---------------- bf16x3 MFMA GEMM, 128x128 tile, BK=32, double-buffered ----------------
// LDS plane per operand: [128 rows][8 chunks of 8 bf16] (128B rows); chunks 0-3 = hi,
// 4-7 = lo, stored at physical chunk p = s ^ (row&7)  (conflict-free ds_read_b128).
// M is runtime (cnt*64). Optional swizzled 1-D grid (proj) + row scatter map.
__global__ __launch_bounds__(256) void gemm3(
    const unsigned short* __restrict__ AH, const unsigned short* __restrict__ AL,
    const unsigned short* __restrict__ BH, const unsigned short* __restrict__ BL,
    const float* __restrict__ bias, float* __restrict__ C,
    const int* __restrict__ Mcnt, int N, int K, long ldc,
    const int* __restrict__ rowmap, int swizMt)
{
    __shared__ __align__(16) unsigned short sm[4 * 8192];   // [buf][A/B][128][64] = 64 KiB
    const int M = Mcnt[0] * 64;
    int bm, bn;
    if (swizMt > 0) {                       // proj: grid.x = 256*swizMt, XCD-grouped M-tiles
        const int f = blockIdx.x, x = f & 7, g = f >> 3;
        const int n = x + 8 * (g / swizMt);
        if (n * 128 >= N) return;
        bm = (g % swizMt) * 128;
        bn = n * 128;
    } else {
        bm = blockIdx.y * 128;
        bn = blockIdx.x * 128;
    }
    if (M == 0 || bm >= M) return;

    const int tid  = threadIdx.x;
    const int lane = tid & 63;
    const int wid  = tid >> 6;
    const int wr = (wid >> 1) * 64, wc = (wid & 1) * 64;

    // staging map: thread -> (row strow within 32-row round, physical chunk stp)
    const int strow = tid >> 3;        // 0..31
    const int stp   = tid & 7;         // physical 16B chunk

    auto stage = [&](int buf, int k0) {
        unsigned short* dstA = sm + (buf * 2 + 0) * 8192;
        unsigned short* dstB = sm + (buf * 2 + 1) * 8192;
        #pragma unroll
        for (int rd = 0; rd < 4; rd++) {
            const int r = rd * 32 + strow;
            const int s = stp ^ (r & 7);                  // logical chunk
            const int karr = (s & 3) * 8;
            const int rowA = min(bm + r, M - 1);
            const unsigned short* srcA = (s < 4 ? AH : AL) + (long)rowA * K + k0 + karr;
            gload16(srcA, dstA + r * 64 + stp * 8);
            const int rowB = min(bn + r, N - 1);
            const unsigned short* srcB = (s < 4 ? BH : BL) + (long)rowB * K + k0 + karr;
            gload16(srcB, dstB + r * 64 + stp * 8);
        }
    };

    f32x4 acc[4][4] = {};
    const int arow = wr + (lane & 15);
    const int brow = wc + (lane & 15);
    const int ch   = lane >> 4;            // k-chunk 0..3

    stage(0, 0);
    __syncthreads();
    int cur = 0;
    for (int k0 = 0; k0 < K; k0 += 32) {
        if (k0 + 32 < K) stage(cur ^ 1, k0 + 32);
        const char* baseA = (const char*)(sm + (cur * 2 + 0) * 8192);
        const char* baseB = (const char*)(sm + (cur * 2 + 1) * 8192);
        bf16x8 ah[4], al[4], bh[4], bl[4];
        #pragma unroll
        for (int m = 0; m < 4; m++) {
            const int r = arow + m * 16;
            ah[m] = *(const bf16x8*)(baseA + r * 128 + (((ch    ) ^ (r & 7)) << 4));
            al[m] = *(const bf16x8*)(baseA + r * 128 + (((ch + 4) ^ (r & 7)) << 4));
        }
        #pragma unroll
        for (int n = 0; n < 4; n++) {
            const int r = brow + n * 16;
            bh[n] = *(const bf16x8*)(baseB + r * 128 + (((ch    ) ^ (r & 7)) << 4));
            bl[n] = *(const bf16x8*)(baseB + r * 128 + (((ch + 4) ^ (r & 7)) << 4));
        }
        #pragma unroll
        for (int m = 0; m < 4; m++) {
            #pragma unroll
            for (int n = 0; n < 4; n++) {
                acc[m][n] = __builtin_amdgcn_mfma_f32_16x16x32_bf16(ah[m], bh[n], acc[m][n], 0, 0, 0);
                acc[m][n] = __builtin_amdgcn_mfma_f32_16x16x32_bf16(ah[m], bl[n], acc[m][n], 0, 0, 0);
                acc[m][n] = __builtin_amdgcn_mfma_f32_16x16x32_bf16(al[m], bh[n], acc[m][n], 0, 0, 0);
            }
        }
        __syncthreads();
        cur ^= 1;
    }

    const int r0 = (lane >> 4) * 4;        // C/D: col=lane&15, row=(lane>>4)*4+j
    #pragma unroll
    for (int n = 0; n < 4; n++) {
        const int gcol = bn + wc + n * 16 + (lane & 15);
        if (gcol >= N) continue;
        const float bv = bias[gcol];
        #pragma unroll
        for (int m = 0; m < 4; m++) {
            #pragma unroll
            for (int j = 0; j < 4; j++) {
                const int grow = bm + wr + m * 16 + r0 + j;
                if (grow >= M) continue;
                const long orow = rowmap ? ((long)rowmap[grow >> 6] * 64 + (grow & 63))
                                         : (long)grow;
                C[orow * ldc + gcol] = acc[m][n][j] + bv;
            }
        }
    }
}

// ---------------- GRU gates: compacted parents -> valid children ----------------
__global__ __launch_bounds__(256) void gru_gates2(const float* __restrict__ gi,
                                                  const float* __restrict__ gh,
                                                  const float* __restrict__ hbufF,
                                                  const int* __restrict__ cntPk,
                                                  const int* __restrict__ listPk,
                                                  const int* __restrict__ posCk,
                                                  float* __restrict__ hidC,      // child f32 (levels<4) or null
                                                  unsigned short* __restrict__ pH,
                                                  unsigned short* __restrict__ pL) {
    const long idx = (long)blockIdx.x * 256 + threadIdx.x;
    const int r = (int)(idx >> 10), c = (int)(idx & 1023);
    if (r >= cntPk[0] * 64) return;
    const int lp = listPk[r >> 6], b = r & 63;
    const float h = hbufF[idx];
    const long g = (long)r * 6144;
    #pragma unroll
    for (int side = 0; side < 2; side++) {
        const int cl = 2 * lp + side;
        const int pc = posCk[cl];
        if (pc < 0) continue;
        const int o3 = side * 3072;
        float ir = gi[g + o3 + c], iz = gi[g + o3 + 1024 + c], in = gi[g + o3 + 2048 + c];
        float hr = gh[g + o3 + c], hz = gh[g + o3 + 1024 + c], hn = gh[g + o3 + 2048 + c];
        float rg = sigm(ir + hr), z = sigm(iz + hz);
        float nn = tanhf(in + rg * hn);
        float hv = (1.0f - z) * nn + z * h;
        const long oc = ((long)pc * 64 + b) * Hh + c;
        dec2(hv, pH[oc], pL[oc]);
        if (hidC) hidC[((long)cl * 64 + b) * Hh + c] = hv;
    }
}

// ---------------- log_softmax (in place on d_out) + mask-zero + fused argmax ----------------
__global__ __launch_bounds__(256) void softmax_argmax(float* __restrict__ outL,
                                                      const int* __restrict__ valid,
                                                      int lbc,
                                                      int* __restrict__ word) {
    const int row = blockIdx.x;
    const int c = row >> 6;
    float* p = outL + (long)row * V1;
    const int t = threadIdx.x;
    if (!valid[lbc + c]) {
        for (int i = t; i < V1; i += 256) p[i] = 0.0f;
        return;
    }
    __shared__ float red[256];
    __shared__ int   redi[256];
    float m = -INFINITY;
    for (int i = t; i < V1; i += 256) m = fmaxf(m, p[i]);
    red[t] = m; __syncthreads();
    for (int s = 128; s > 0; s >>= 1) { if (t < s) red[t] = fmaxf(red[t], red[t + s]); __syncthreads(); }
    m = red[0]; __syncthreads();
    float sum = 0.0f;
    for (int i = t; i < V1; i += 256) sum += expf(p[i] - m);
    red[t] = sum; __syncthreads();
    for (int s = 128; s > 0; s >>= 1) { if (t < s) red[t] += red[t + s]; __syncthreads(); }
    const float L = m + logf(red[0]);
    __syncthreads();
    // write pass + argmax over the stored values (matches reference argmax(prod))
    float best = -INFINITY; int bidx = V1;
    for (int i = t; i < V1; i += 256) {
        float v = p[i] - L;
        p[i] = v;
        if (v > best) { best = v; bidx = i; }
    }
    red[t] = best; redi[t] = bidx; __syncthreads();
    for (int s = 128; s > 0; s >>= 1) {
        if (t < s) {
            float v2 = red[t + s]; int i2 = redi[t + s];
            if (v2 > red[t] || (v2 == red[t] && i2 < redi[t])) { red[t] = v2; redi[t] = i2; }
        }
        __syncthreads();
    }
    if (t == 0) word[row] = redi[0];
}

// =================== fallback fp32 path kernels (round-1) ===================
__global__ __launch_bounds__(256) void argmax_rows(const float* __restrict__ P,
                                                   int* __restrict__ word) {
    const int row = blockIdx.x;
    const float* p = P + (long)row * V1;
    const int t = threadIdx.x;
    float best = -INFINITY; int bidx = V1;
    for (int i = t; i < V1; i += 256) {
        float v = p[i];
        if (v > best) { best = v; bidx = i; }
    }
    __shared__ float sv[256]; __shared__ int si[256];
    sv[t] = best; si[t] = bidx; __syncthreads();
    for (int s = 128; s > 0; s >>= 1) {
        if (t < s) {
            float v2 = sv[t + s]; int i2 = si[t + s];
            if (v2 > sv[t] || (v2 == sv[t] && i2 < si[t])) { sv[t] = v2; si[t] = i2; }
        }
        __syncthreads();
    }
    if (t == 0) word[row] = si[0];
}
__global__ __launch_bounds__(256) void gather_emb(const float* __restrict__ emb,
                                                  const int* __restrict__ word,
                                                  float* __restrict__ xbuf) {
    const int r = blockIdx.x;
    const int t = threadIdx.x;
    ((float4*)(xbuf + (long)r * Hh))[t] = ((const float4*)(emb + (long)word[r] * Hh))[t];
}
__global__ __launch_bounds__(256) void gemm_nt_bias(const float* __restrict__ A,
                                                    const float* __restrict__ W,
                                                    const float* __restrict__ bias,
                                                    float* __restrict__ C,
                                                    int N, int K, long ldc) {
    __shared__ float As[16][65];
    __shared__ float Ws[16][65];
    const int bm = blockIdx.y * 64;
    const int bn = blockIdx.x * 64;
    const int tid = threadIdx.x;
    const int tx = tid & 15, ty = tid >> 4;
    const int lr = tid >> 2;
    const int lk = (tid & 3) * 4;
    float acc[4][4] = {};
    for (int k0 = 0; k0 < K; k0 += 16) {
        float4 av = *(const float4*)(A + (long)(bm + lr) * K + k0 + lk);
        float4 wv = make_float4(0.f, 0.f, 0.f, 0.f);
        const int wn = bn + lr;
        if (wn < N) wv = *(const float4*)(W + (long)wn * K + k0 + lk);
        As[lk + 0][lr] = av.x; As[lk + 1][lr] = av.y; As[lk + 2][lr] = av.z; As[lk + 3][lr] = av.w;
        Ws[lk + 0][lr] = wv.x; Ws[lk + 1][lr] = wv.y; Ws[lk + 2][lr] = wv.z; Ws[lk + 3][lr] = wv.w;
        __syncthreads();
        #pragma unroll
        for (int kk = 0; kk < 16; kk++) {
            float a[4], w2[4];
            #pragma unroll
            for (int i = 0; i < 4; i++) a[i] = As[kk][ty * 4 + i];
            #pragma unroll
            for (int j = 0; j < 4; j++) w2[j] = Ws[kk][tx * 4 + j];
            #pragma unroll
            for (int i = 0; i < 4; i++)
                #pragma unroll
                for (int j = 0; j < 4; j++)
                    acc[i][j] += a[i] * w2[j];
        }
        __syncthreads();
    }
    #pragma unroll
    for (int i = 0; i < 4; i++)
        #pragma unroll
        for (int j = 0; j < 4; j++) {
            int n = bn + tx * 4 + j;
            if (n < N) C[(long)(bm + ty * 4 + i) * ldc + n] = acc[i][j] + bias[n];
        }
}
__global__ __launch_bounds__(256) void gru_gates_f32(const float* __restrict__ gil,
                                                     const float* __restrict__ ghl,
                                                     const float* __restrict__ gir,
                                                     const float* __restrict__ ghr,
                                                     const float* __restrict__ hprev,
                                                     float* __restrict__ hchild,
                                                     int rows) {
    long idx = (long)blockIdx.x * 256 + threadIdx.x;
    if (idx >= (long)rows * Hh) return;
    const int r = (int)(idx / Hh), c = (int)(idx % Hh);
    const int p = r / Bb, b = r % Bb;
    const float h = hprev[(long)r * Hh + c];
    const long g = (long)r * 3072;
    {
        float ir = gil[g + c], iz = gil[g + Hh + c], in = gil[g + 2 * Hh + c];
        float hr = ghl[g + c], hz = ghl[g + Hh + c], hn = ghl[g + 2 * Hh + c];
        float rg = sigm(ir + hr), z = sigm(iz + hz);
        float n = tanhf(in + rg * hn);
        hchild[((long)(2 * p) * Bb + b) * Hh + c] = (1.0f - z) * n + z * h;
    }
    {
        float ir = gir[g + c], iz = gir[g + Hh + c], in = gir[g + 2 * Hh + c];
        float hr = ghr[g + c], hz = ghr[g + Hh + c], hn = ghr[g + 2 * Hh + c];
        float rg = sigm(ir + hr), z = sigm(iz + hz);
        float n = tanhf(in + rg * hn);
        hchild[((long)(2 * p + 1) * Bb + b) * Hh + c] = (1.0f - z) * n + z * h;
    }
}
__global__ __launch_bounds__(256) void logsoftmax_mask(float* __restrict__ P,
                                                       const int* __restrict__ valid,
                                                       int nodeBase) {
    const int row = blockIdx.x;
    const int node = nodeBase + row / Bb;
    float* p = P + (long)row * V1;
    const int t = threadIdx.x;
    if (!valid[node]) {
        for (int i = t; i < V1; i += 256) p[i] = 0.0f;
        return;
    }
    __shared__ float red[256];
    float m = -INFINITY;
    for (int i = t; i < V1; i += 256) m = fmaxf(m, p[i]);
    red[t] = m; __syncthreads();
    for (int s = 128; s > 0; s >>= 1) { if (t < s) red[t] = fmaxf(red[t], red[t + s]); __syncthreads(); }
    m = red[0]; __syncthreads();
    float sum = 0.0f;
    for (int i = t; i < V1; i += 256) sum += expf(p[i] - m);
    red[t] = sum; __syncthreads();
    for (int s = 128; s > 0; s >>= 1) { if (t < s) red[t] += red[t + s]; __syncthreads(); }
    const float L = m + logf(red[0]);
    for (int i = t; i < V1; i += 256) p[i] = p[i] - L;
}
__global__ void compute_valid(const int* __restrict__ null_rand, int* __restrict__ valid) {
    if (threadIdx.x == 0 && blockIdx.x == 0) {
        valid[0] = (null_rand[0] != 0) ? 1 : 0;
        for (int i = 1; i < 31; i++)
            valid[i] = (valid[(i - 1) / 2] && (null_rand[i] != 0)) ? 1 : 0;
    }
}

extern "C" void kernel_launch(void* const* d_in, const int* in_sizes, int n_in,
                              void* d_out, int out_size, void* d_ws, size_t ws_size,
                              hipStream_t stream) {
    const float* encoding = (const float*)d_in[0];
    const float* emb      = (const float*)d_in[1];
    const float* Wl_ih    = (const float*)d_in[2];
    const float* Wl_hh    = (const float*)d_in[3];
    const float* bl_ih    = (const float*)d_in[4];
    const float* bl_hh    = (const float*)d_in[5];
    const float* Wr_ih    = (const float*)d_in[6];
    const float* Wr_hh    = (const float*)d_in[7];
    const float* br_ih    = (const float*)d_in[8];
    const float* br_hh    = (const float*)d_in[9];
    const float* Wout     = (const float*)d_in[10];
    const float* bout     = (const float*)d_in[11];
    const int*   null_rand= (const int*)d_in[12];
    float* out = (float*)d_out;

    // ---- fast-path workspace layout (~221 MB) ----
    char* w = (char*)d_ws;
    size_t off = 0;
    auto take = [&](size_t bytes) -> char* {
        char* p = w + off;
        off += (bytes + 255) & ~(size_t)255;
        return p;
    };
    float*          hid   = (float*)take(15L * NH * 4);          // nodes 0..14 f32
    unsigned short* xH    = (unsigned short*)take(512L * Hh * 2);
    unsigned short* xL    = (unsigned short*)take(512L * Hh * 2);
    unsigned short* hH    = (unsigned short*)take(512L * Hh * 2);
    unsigned short* hL    = (unsigned short*)take(512L * Hh * 2);
    float*          hbufF = (float*)take(512L * Hh * 4);
    unsigned short* pH    = (unsigned short*)take(1024L * Hh * 2);
    unsigned short* pL    = (unsigned short*)take(1024L * Hh * 2);
    float*          gi    = (float*)take(512L * 6144 * 4);
    float*          gh    = (float*)take(512L * 6144 * 4);
    unsigned short* WoutH = (unsigned short*)take(32769024L * 2);
    unsigned short* WoutL = (unsigned short*)take(32769024L * 2);
    unsigned short* WihH  = (unsigned short*)take(6291456L * 2);
    unsigned short* WihL  = (unsigned short*)take(6291456L * 2);
    unsigned short* WhhH  = (unsigned short*)take(6291456L * 2);
    unsigned short* WhhL  = (unsigned short*)take(6291456L * 2);
    float*          bih   = (float*)take(6144L * 4);
    float*          bhh   = (float*)take(6144L * 4);
    int*            word  = (int*)take(1024L * 4);
    int*            valid = (int*)take(31L * 4);
    int*            cntP  = (int*)take(4L * 4);
    int*            cntC  = (int*)take(4L * 4);
    int*            listP = (int*)take(32L * 4);
    int*            listC = (int*)take(64L * 4);
    int*            posC  = (int*)take(64L * 4);
    const bool fastok = (off <= ws_size);

    if (fastok) {
        build_meta<<<1, 64, 0, stream>>>(null_rand, valid, cntP, listP, cntC, listC, posC);
        decompose_f32<<<2048, 256, 0, stream>>>(Wout,  WoutH, WoutL, 8192256L);
        decompose_f32<<<1024, 256, 0, stream>>>(Wl_ih, WihH,           WihL,           786432L);
        decompose_f32<<<1024, 256, 0, stream>>>(Wr_ih, WihH + 3145728, WihL + 3145728, 786432L);
        decompose_f32<<<1024, 256, 0, stream>>>(Wl_hh, WhhH,           WhhL,           786432L);
        decompose_f32<<<1024, 256, 0, stream>>>(Wr_hh, WhhH + 3145728, WhhL + 3145728, 786432L);
        cat_bias<<<12, 256, 0, stream>>>(bl_ih, br_ih, bih);
        cat_bias<<<12, 256, 0, stream>>>(bl_hh, br_hh, bhh);
        set_word0<<<1, 64, 0, stream>>>(word);
        copy_f4<<<64, 256, 0, stream>>>((const float4*)encoding, (float4*)hid, 16384L);
        const long n0 = (long)Bb * V1;
        zero_buf<<<(int)((n0 + 255) / 256), 256, 0, stream>>>(out, n0);

        for (int k = 0; k < 4; k++) {
            const int npMax = 1 << k;              // parents this level (max)
            const int ncMax = 2 << k;              // children (max)
            const int MtP = (npMax * 64 + 127) / 128;   // 1,1,2,4
            const int MtC = (ncMax * 64) / 128;         // 1,2,4,8
            const long lbk = (1L << k) - 1;
            const long lbc = (2L << k) - 1;
            float* outL = out + lbc * Bb * V1;

            gather_pack<<<npMax * 64, 256, 0, stream>>>(
                emb, hid + lbk * NH, word, listP + k * 8, cntP + k,
                xH, xL, hH, hL, hbufF);

            dim3 gg(48, MtP);
            gemm3<<<gg, 256, 0, stream>>>(xH, xL, WihH, WihL, bih, gi,
                                          cntP + k, 6144, 1024, 6144, nullptr, 0);
            gemm3<<<gg, 256, 0, stream>>>(hH, hL, WhhH, WhhL, bhh, gh,
                                          cntP + k, 6144, 1024, 6144, nullptr, 0);

            gru_gates2<<<npMax * 256, 256, 0, stream>>>(
                gi, gh, hbufF, cntP + k, listP + k * 8, posC + k * 16,
                (k < 3) ? hid + lbc * NH : nullptr, pH, pL);

            gemm3<<<256 * MtC, 256, 0, stream>>>(pH, pL, WoutH, WoutL, bout, outL,
                                                 cntC + k, V1, 1024, V1,
                                                 listC + k * 16, MtC);

            softmax_argmax<<<ncMax * 64, 256, 0, stream>>>(outL, valid, (int)lbc, word);
        }
        return;
    }

    // ---------------- fallback: fp32 path (~35 MB ws) ----------------
    float* f_hid  = (float*)d_ws;
    float* f_xbuf = f_hid  + 31L * NH;
    float* f_gil  = f_xbuf + 512L * Hh;
    float* f_ghl  = f_gil  + 512L * 3072;
    float* f_gir  = f_ghl  + 512L * 3072;
    float* f_ghr  = f_gir  + 512L * 3072;
    int*   f_word = (int*)(f_ghr + 512L * 3072);
    int*   f_valid= f_word + 512;

    compute_valid<<<1, 64, 0, stream>>>(null_rand, f_valid);
    copy_f4<<<64, 256, 0, stream>>>((const float4*)encoding, (float4*)f_hid, 16384L);
    const long n0 = (long)Bb * V1;
    zero_buf<<<(int)((n0 + 255) / 256), 256, 0, stream>>>(out, n0);

    for (int k = 0; k < 4; k++) {
        const int  rows = (1 << k) * Bb;
        const long lbk  = (1L << k) - 1;
        const long lbc  = (2L << k) - 1;

        argmax_rows<<<rows, 256, 0, stream>>>(out + lbk * Bb * V1, f_word);
        gather_emb<<<rows, 256, 0, stream>>>(emb, f_word, f_xbuf);

        dim3 gg(48, rows / 64);
        const float* hk = f_hid + lbk * NH;
        gemm_nt_bias<<<gg, 256, 0, stream>>>(f_xbuf, Wl_ih, bl_ih, f_gil, 3072, 1024, 3072);
        gemm_nt_bias<<<gg, 256, 0, stream>>>(hk,     Wl_hh, bl_hh, f_ghl, 3072, 1024, 3072);
        gemm_nt_bias<<<gg, 256, 0, stream>>>(f_xbuf, Wr_ih, br_ih, f_gir, 3072, 1024, 3072);
        gemm_nt_bias<<<gg, 256, 0, stream>>>(hk,     Wr_hh, br_hh, f_ghr, 3072, 1024, 3072);

        const long tot = (long)rows * Hh;
        gru_gates_f32<<<(int)((tot + 255) / 256), 256, 0, stream>>>(
            f_gil, f_ghl, f_gir, f_ghr, hk, f_hid + lbc * NH, rows);

        dim3 gp((V1 + 63) / 64, 2 * rows / 64);
        gemm_nt_bias<<<gp, 256, 0, stream>>>(f_hid + lbc * NH, Wout, bout,
                                             out + lbc * Bb * V1, V1, 1024, V1);
        logsoftmax_mask<<<2 * rows, 256, 0, stream>>>(out + lbc * Bb * V1, f_valid, (int)lbc);
    }
}

// Round 4
// 81.129 us; speedup vs baseline: 50.4659x; 2.4264x over previous
//
#include <hip/hip_runtime.h>
#include <math.h>

// MitosisDecoder: depth-4 binary GRU tree decoder. H=1024, B=64, V+1=32001,
// 31 nodes (heap). out = log_softmax per node, masked by heap validity.
// Validity-pruned bf16x3 split-precision MFMA GEMMs; all heavy work gated on
// device-side validity (seed-0 input has null root -> output all zeros, so the
// only mandatory work is the 254 MB zero-fill).

constexpr int Hh  = 1024;
constexpr int Bb  = 64;
constexpr int V1  = 32001;
constexpr long NH = (long)Bb * Hh;

typedef __bf16 bf16x8 __attribute__((ext_vector_type(8)));
typedef float  f32x4  __attribute__((ext_vector_type(4)));

__device__ __forceinline__ float sigm(float x) { return 1.0f / (1.0f + expf(-x)); }

__device__ __forceinline__ unsigned short f2bf(float x) {
    unsigned int u = __builtin_bit_cast(unsigned int, x);
    u = (u + 0x7fffu + ((u >> 16) & 1u)) >> 16;
    return (unsigned short)u;
}
__device__ __forceinline__ float bf2f(unsigned short b) {
    unsigned int u = ((unsigned int)b) << 16;
    return __builtin_bit_cast(float, u);
}
__device__ __forceinline__ void dec2(float v, unsigned short& hi, unsigned short& lo) {
    hi = f2bf(v);
    lo = f2bf(v - bf2f(hi));
}
__device__ __forceinline__ void dec4(float4 v, ushort4& h, ushort4& l) {
    dec2(v.x, h.x, l.x); dec2(v.y, h.y, l.y); dec2(v.z, h.z, l.z); dec2(v.w, h.w, l.w);
}
__device__ __forceinline__ void gload16(const unsigned short* g, unsigned short* l) {
    __builtin_amdgcn_global_load_lds((__attribute__((address_space(1))) void*)g,
                                     (__attribute__((address_space(3))) void*)l,
                                     16, 0, 0);
}

// ---- meta: validity heap, compaction lists, bias concat (1 block) ----
__global__ __launch_bounds__(256) void build_meta(
    const int* __restrict__ null_rand, int* __restrict__ valid,
    int* __restrict__ cntP, int* __restrict__ listP,
    int* __restrict__ cntC, int* __restrict__ listC, int* __restrict__ posC,
    const float* __restrict__ bl_ih, const float* __restrict__ br_ih,
    const float* __restrict__ bl_hh, const float* __restrict__ br_hh,
    float* __restrict__ bih, float* __restrict__ bhh) {
    const int t = threadIdx.x;
    if (t == 0) {
        valid[0] = (null_rand[0] != 0) ? 1 : 0;
        for (int i = 1; i < 31; i++)
            valid[i] = (valid[(i - 1) / 2] && (null_rand[i] != 0)) ? 1 : 0;
        for (int k = 0; k < 4; k++) {
            int np = 0;
            for (int p = 0; p < (1 << k); p++)
                if (valid[(1 << k) - 1 + p]) listP[k * 8 + np++] = p;
            cntP[k] = np;
            int nc = 0;
            for (int c = 0; c < (2 << k); c++) {
                if (valid[(2 << k) - 1 + c]) { posC[k * 16 + c] = nc; listC[k * 16 + nc] = c; nc++; }
                else posC[k * 16 + c] = -1;
            }
            cntC[k] = nc;
        }
    }
    for (int i = t; i < 3072; i += 256) {
        bih[i] = bl_ih[i]; bih[3072 + i] = br_ih[i];
        bhh[i] = bl_hh[i]; bhh[3072 + i] = br_hh[i];
    }
}

// ---- whole-output zero (mandatory floor: 254 MB) ----
__global__ __launch_bounds__(256) void zero_out(float4* __restrict__ p, long n4) {
    const float4 z = make_float4(0.f, 0.f, 0.f, 0.f);
    for (long i = (long)blockIdx.x * 256 + threadIdx.x; i < n4; i += (long)gridDim.x * 256)
        p[i] = z;
}

// ---- all weights f32 -> hi/lo bf16 planes; gated on root validity ----
__global__ __launch_bounds__(256) void decompose_all(
    const float* __restrict__ Wout, const float* __restrict__ Wlih,
    const float* __restrict__ Wrih, const float* __restrict__ Wlhh,
    const float* __restrict__ Wrhh,
    unsigned short* __restrict__ WoutH, unsigned short* __restrict__ WoutL,
    unsigned short* __restrict__ WihH,  unsigned short* __restrict__ WihL,
    unsigned short* __restrict__ WhhH,  unsigned short* __restrict__ WhhL,
    const int* __restrict__ gate) {
    if (gate[0] == 0) return;
    const long nW = 8192256L;   // Wout float4s
    const long nG = 786432L;    // each GRU weight half float4s
    for (long i = (long)blockIdx.x * 256 + threadIdx.x; i < nW + 4 * nG;
         i += (long)gridDim.x * 256) {
        const float4* src; ushort4 *dh, *dl; long j;
        if (i < nW) {
            src = (const float4*)Wout; j = i;
            dh = (ushort4*)WoutH; dl = (ushort4*)WoutL;
        } else {
            long q = i - nW; int seg = (int)(q / nG); j = q % nG;
            src = (const float4*)(seg == 0 ? Wlih : seg == 1 ? Wrih : seg == 2 ? Wlhh : Wrhh);
            dh = (ushort4*)(seg < 2 ? WihH : WhhH) + (seg & 1) * nG;
            dl = (ushort4*)(seg < 2 ? WihL : WhhL) + (seg & 1) * nG;
        }
        ushort4 h, l;
        dec4(src[j], h, l);
        dh[j] = h; dl[j] = l;
    }
}

// ---- level-0 operands: x = emb[argmax(zeros)=0], h = encoding; gated ----
__global__ __launch_bounds__(256) void init_l0(
    const float* __restrict__ encoding, const float* __restrict__ emb,
    const int* __restrict__ gate,
    unsigned short* __restrict__ xH, unsigned short* __restrict__ xL,
    unsigned short* __restrict__ hH, unsigned short* __restrict__ hL,
    float* __restrict__ hbufF) {
    if (gate[0] == 0) return;
    const int b = blockIdx.x, t = threadIdx.x;
    float4 xv = ((const float4*)emb)[t];                       // emb row 0
    float4 hv = ((const float4*)(encoding + (long)b * Hh))[t];
    ushort4 h4, l4;
    dec4(xv, h4, l4);
    ((ushort4*)(xH + (long)b * Hh))[t] = h4;
    ((ushort4*)(xL + (long)b * Hh))[t] = l4;
    dec4(hv, h4, l4);
    ((ushort4*)(hH + (long)b * Hh))[t] = h4;
    ((ushort4*)(hL + (long)b * Hh))[t] = l4;
    ((float4*)(hbufF + (long)b * Hh))[t] = hv;
}

// ---- bf16x3 MFMA GEMM body: 128x128 tile, BK=32, double-buffered, XOR-swz LDS ----
__device__ __forceinline__ void gemm3_body(
    const unsigned short* __restrict__ AH, const unsigned short* __restrict__ AL,
    const unsigned short* __restrict__ BH, const unsigned short* __restrict__ BL,
    const float* __restrict__ bias, float* __restrict__ C,
    const int* __restrict__ rowmap,
    int M, int N, int K, long ldc, int bm, int bn,
    unsigned short* sm /* 4*8192 elems */) {
    const int tid  = threadIdx.x;
    const int lane = tid & 63;
    const int wid  = tid >> 6;
    const int wr = (wid >> 1) * 64, wc = (wid & 1) * 64;
    const int strow = tid >> 3;        // 0..31
    const int stp   = tid & 7;         // physical 16B chunk

    auto stage = [&](int buf, int k0) {
        unsigned short* dstA = sm + (buf * 2 + 0) * 8192;
        unsigned short* dstB = sm + (buf * 2 + 1) * 8192;
        #pragma unroll
        for (int rd = 0; rd < 4; rd++) {
            const int r = rd * 32 + strow;
            const int s = stp ^ (r & 7);
            const int karr = (s & 3) * 8;
            const int rowA = min(bm + r, M - 1);
            gload16((s < 4 ? AH : AL) + (long)rowA * K + k0 + karr, dstA + r * 64 + stp * 8);
            const int rowB = min(bn + r, N - 1);
            gload16((s < 4 ? BH : BL) + (long)rowB * K + k0 + karr, dstB + r * 64 + stp * 8);
        }
    };

    f32x4 acc[4][4] = {};
    const int arow = wr + (lane & 15);
    const int brow = wc + (lane & 15);
    const int ch   = lane >> 4;

    stage(0, 0);
    __syncthreads();
    int cur = 0;
    for (int k0 = 0; k0 < K; k0 += 32) {
        if (k0 + 32 < K) stage(cur ^ 1, k0 + 32);
        const char* baseA = (const char*)(sm + (cur * 2 + 0) * 8192);
        const char* baseB = (const char*)(sm + (cur * 2 + 1) * 8192);
        bf16x8 ah[4], al[4], bh[4], bl[4];
        #pragma unroll
        for (int m = 0; m < 4; m++) {
            const int r = arow + m * 16;
            ah[m] = *(const bf16x8*)(baseA + r * 128 + (((ch    ) ^ (r & 7)) << 4));
            al[m] = *(const bf16x8*)(baseA + r * 128 + (((ch + 4) ^ (r & 7)) << 4));
        }
        #pragma unroll
        for (int n = 0; n < 4; n++) {
            const int r = brow + n * 16;
            bh[n] = *(const bf16x8*)(baseB + r * 128 + (((ch    ) ^ (r & 7)) << 4));
            bl[n] = *(const bf16x8*)(baseB + r * 128 + (((ch + 4) ^ (r & 7)) << 4));
        }
        #pragma unroll
        for (int m = 0; m < 4; m++) {
            #pragma unroll
            for (int n = 0; n < 4; n++) {
                acc[m][n] = __builtin_amdgcn_mfma_f32_16x16x32_bf16(ah[m], bh[n], acc[m][n], 0, 0, 0);
                acc[m][n] = __builtin_amdgcn_mfma_f32_16x16x32_bf16(ah[m], bl[n], acc[m][n], 0, 0, 0);
                acc[m][n] = __builtin_amdgcn_mfma_f32_16x16x32_bf16(al[m], bh[n], acc[m][n], 0, 0, 0);
            }
        }
        __syncthreads();
        cur ^= 1;
    }

    const int r0 = (lane >> 4) * 4;        // C/D: col=lane&15, row=(lane>>4)*4+j
    #pragma unroll
    for (int n = 0; n < 4; n++) {
        const int gcol = bn + wc + n * 16 + (lane & 15);
        if (gcol >= N) continue;
        const float bv = bias[gcol];
        #pragma unroll
        for (int m = 0; m < 4; m++) {
            #pragma unroll
            for (int j = 0; j < 4; j++) {
                const int grow = bm + wr + m * 16 + r0 + j;
                if (grow >= M) continue;
                const long orow = rowmap ? ((long)rowmap[grow >> 6] * 64 + (grow & 63))
                                         : (long)grow;
                C[orow * ldc + gcol] = acc[m][n][j] + bv;
            }
        }
    }
}

// both GRU GEMMs (gi and gh) in one launch: grid.y = 2*MtP
__global__ __launch_bounds__(256) void gemm3_gru(
    const unsigned short* __restrict__ xH, const unsigned short* __restrict__ xL,
    const unsigned short* __restrict__ hH, const unsigned short* __restrict__ hL,
    const unsigned short* __restrict__ WihH, const unsigned short* __restrict__ WihL,
    const unsigned short* __restrict__ WhhH, const unsigned short* __restrict__ WhhL,
    const float* __restrict__ bih, const float* __restrict__ bhh,
    float* __restrict__ gi, float* __restrict__ gh,
    const int* __restrict__ Mcnt, int MtP) {
    __shared__ __align__(16) unsigned short sm[4 * 8192];
    const int M = Mcnt[0] * 64;
    const int half = (int)blockIdx.y >= MtP;
    const int bm = ((int)blockIdx.y - half * MtP) * 128;
    if (M == 0 || bm >= M) return;
    gemm3_body(half ? hH : xH, half ? hL : xL,
               half ? WhhH : WihH, half ? WhhL : WihL,
               half ? bhh : bih, half ? gh : gi, nullptr,
               M, 6144, 1024, 6144, bm, (int)blockIdx.x * 128, sm);
}

// projection GEMM: swizzled 1-D grid (XCD-grouped M-tiles), scattered C rows
__global__ __launch_bounds__(256) void gemm3_proj(
    const unsigned short* __restrict__ pH, const unsigned short* __restrict__ pL,
    const unsigned short* __restrict__ WoutH, const unsigned short* __restrict__ WoutL,
    const float* __restrict__ bout, float* __restrict__ outL,
    const int* __restrict__ Mcnt, const int* __restrict__ rowmap, int MtC) {
    __shared__ __align__(16) unsigned short sm[4 * 8192];
    const int M = Mcnt[0] * 64;
    const int f = blockIdx.x, x = f & 7, g = f >> 3;
    const int n = x + 8 * (g / MtC);
    if (n * 128 >= V1) return;
    const int bm = (g % MtC) * 128;
    if (M == 0 || bm >= M) return;
    gemm3_body(pH, pL, WoutH, WoutL, bout, outL, rowmap,
               M, V1, 1024, (long)V1, bm, n * 128, sm);
}

// ---- GRU gates: compacted parents -> valid children (compacted pH/pL) ----
__global__ __launch_bounds__(256) void gru_gates2(
    const float* __restrict__ gi, const float* __restrict__ gh,
    const float* __restrict__ hbufF,
    const int* __restrict__ cntPk, const int* __restrict__ listPk,
    const int* __restrict__ posCk,
    float* __restrict__ hidC,
    unsigned short* __restrict__ pH, unsigned short* __restrict__ pL) {
    const long idx = (long)blockIdx.x * 256 + threadIdx.x;
    const int r = (int)(idx >> 10), c = (int)(idx & 1023);
    if (r >= cntPk[0] * 64) return;
    const int lp = listPk[r >> 6], b = r & 63;
    const float h = hbufF[idx];
    const long g = (long)r * 6144;
    #pragma unroll
    for (int side = 0; side < 2; side++) {
        const int cl = 2 * lp + side;
        const int pc = posCk[cl];
        if (pc < 0) continue;
        const int o3 = side * 3072;
        float ir = gi[g + o3 + c], iz = gi[g + o3 + 1024 + c], in = gi[g + o3 + 2048 + c];
        float hr = gh[g + o3 + c], hz = gh[g + o3 + 1024 + c], hn = gh[g + o3 + 2048 + c];
        float rg = sigm(ir + hr), z = sigm(iz + hz);
        float nn = tanhf(in + rg * hn);
        float hv = (1.0f - z) * nn + z * h;
        const long oc = ((long)pc * 64 + b) * Hh + c;
        dec2(hv, pH[oc], pL[oc]);
        if (hidC) hidC[((long)cl * 64 + b) * Hh + c] = hv;
    }
}

// ---- log_softmax (valid rows only, compacted) + fused argmax + next-level gather ----
__global__ __launch_bounds__(256) void softmax_gather(
    float* __restrict__ outL,
    const int* __restrict__ cntCk, const int* __restrict__ listCk,
    const float* __restrict__ emb, const float* __restrict__ hidC, // null at leaf
    unsigned short* __restrict__ xH, unsigned short* __restrict__ xL,
    unsigned short* __restrict__ hH, unsigned short* __restrict__ hL,
    float* __restrict__ hbufF) {
    const int r = blockIdx.x;
    if (r >= cntCk[0] * 64) return;
    const int c = listCk[r >> 6], b = r & 63;
    float* p = outL + ((long)c * 64 + b) * V1;
    const int t = threadIdx.x;
    __shared__ float rm[256], rs[256];
    __shared__ int   ri[256];
    // single-pass online max + expsum
    float m = -INFINITY, s = 0.f;
    for (int i = t; i < V1; i += 256) {
        float v = p[i];
        float M = fmaxf(m, v);
        s = s * expf(m - M) + expf(v - M);
        m = M;
    }
    rm[t] = m; rs[t] = s; __syncthreads();
    for (int st = 128; st > 0; st >>= 1) {
        if (t < st) {
            float m2 = rm[t + st], s2 = rs[t + st];
            float M = fmaxf(rm[t], m2);
            rs[t] = rs[t] * expf(rm[t] - M) + s2 * expf(m2 - M);
            rm[t] = M;
        }
        __syncthreads();
    }
    const float L = rm[0] + logf(rs[0]);
    __syncthreads();
    // write pass + argmax over stored values (reference: argmax(prod))
    float best = -INFINITY; int bidx = V1;
    for (int i = t; i < V1; i += 256) {
        float v = p[i] - L;
        p[i] = v;
        if (v > best) { best = v; bidx = i; }
    }
    rm[t] = best; ri[t] = bidx; __syncthreads();
    for (int st = 128; st > 0; st >>= 1) {
        if (t < st) {
            float v2 = rm[t + st]; int i2 = ri[t + st];
            if (v2 > rm[t] || (v2 == rm[t] && i2 < ri[t])) { rm[t] = v2; ri[t] = i2; }
        }
        __syncthreads();
    }
    if (!hidC) return;
    // fused gather for next level: this valid child is next level's parent,
    // compacted row index r (listP[k+1] == listC[k] ordering).
    const int widx = ri[0];
    float4 xv = ((const float4*)(emb + (long)widx * Hh))[t];
    float4 hv = ((const float4*)(hidC + ((long)c * 64 + b) * Hh))[t];
    ushort4 h4, l4;
    dec4(xv, h4, l4);
    ((ushort4*)(xH + (long)r * Hh))[t] = h4;
    ((ushort4*)(xL + (long)r * Hh))[t] = l4;
    dec4(hv, h4, l4);
    ((ushort4*)(hH + (long)r * Hh))[t] = h4;
    ((ushort4*)(hL + (long)r * Hh))[t] = l4;
    ((float4*)(hbufF + (long)r * Hh))[t] = hv;
}

extern "C" void kernel_launch(void* const* d_in, const int* in_sizes, int n_in,
                              void* d_out, int out_size, void* d_ws, size_t ws_size,
                              hipStream_t stream) {
    const float* encoding = (const float*)d_in[0];
    const float* emb      = (const float*)d_in[1];
    const float* Wl_ih    = (const float*)d_in[2];
    const float* Wl_hh    = (const float*)d_in[3];
    const float* bl_ih    = (const float*)d_in[4];
    const float* bl_hh    = (const float*)d_in[5];
    const float* Wr_ih    = (const float*)d_in[6];
    const float* Wr_hh    = (const float*)d_in[7];
    const float* br_ih    = (const float*)d_in[8];
    const float* br_hh    = (const float*)d_in[9];
    const float* Wout     = (const float*)d_in[10];
    const float* bout     = (const float*)d_in[11];
    const int*   null_rand= (const int*)d_in[12];
    float* out = (float*)d_out;

    char* w = (char*)d_ws;
    size_t off = 0;
    auto take = [&](size_t bytes) -> char* {
        char* p = w + off;
        off += (bytes + 255) & ~(size_t)255;
        return p;
    };
    float*          hid   = (float*)take(15L * NH * 4);          // nodes 0..14 (0 unused)
    unsigned short* xH    = (unsigned short*)take(512L * Hh * 2);
    unsigned short* xL    = (unsigned short*)take(512L * Hh * 2);
    unsigned short* hH    = (unsigned short*)take(512L * Hh * 2);
    unsigned short* hL    = (unsigned short*)take(512L * Hh * 2);
    float*          hbufF = (float*)take(512L * Hh * 4);
    unsigned short* pH    = (unsigned short*)take(1024L * Hh * 2);
    unsigned short* pL    = (unsigned short*)take(1024L * Hh * 2);
    float*          gi    = (float*)take(512L * 6144 * 4);
    float*          gh    = (float*)take(512L * 6144 * 4);
    unsigned short* WoutH = (unsigned short*)take(32769024L * 2);
    unsigned short* WoutL = (unsigned short*)take(32769024L * 2);
    unsigned short* WihH  = (unsigned short*)take(6291456L * 2);
    unsigned short* WihL  = (unsigned short*)take(6291456L * 2);
    unsigned short* WhhH  = (unsigned short*)take(6291456L * 2);
    unsigned short* WhhL  = (unsigned short*)take(6291456L * 2);
    float*          bih   = (float*)take(6144L * 4);
    float*          bhh   = (float*)take(6144L * 4);
    int*            valid = (int*)take(31L * 4);
    int*            cntP  = (int*)take(4L * 4);
    int*            cntC  = (int*)take(4L * 4);
    int*            listP = (int*)take(32L * 4);
    int*            listC = (int*)take(64L * 4);
    int*            posC  = (int*)take(64L * 4);
    (void)ws_size;  // rounds 2-3 confirmed ws_size >= this layout (~221 MB)

    build_meta<<<1, 256, 0, stream>>>(null_rand, valid, cntP, listP, cntC, listC, posC,
                                      bl_ih, br_ih, bl_hh, br_hh, bih, bhh);
    zero_out<<<2048, 256, 0, stream>>>((float4*)out, (long)out_size / 4);
    decompose_all<<<1024, 256, 0, stream>>>(Wout, Wl_ih, Wr_ih, Wl_hh, Wr_hh,
                                            WoutH, WoutL, WihH, WihL, WhhH, WhhL, valid);
    init_l0<<<64, 256, 0, stream>>>(encoding, emb, valid, xH, xL, hH, hL, hbufF);

    for (int k = 0; k < 4; k++) {
        const int npMax = 1 << k;
        const int ncMax = 2 << k;
        const int MtP = (npMax * 64 + 127) / 128;   // 1,1,2,4
        const int MtC = (ncMax * 64) / 128;         // 1,2,4,8
        const long lbc = (2L << k) - 1;
        float* outL = out + lbc * Bb * V1;

        gemm3_gru<<<dim3(48, 2 * MtP), 256, 0, stream>>>(
            xH, xL, hH, hL, WihH, WihL, WhhH, WhhL, bih, bhh, gi, gh, cntP + k, MtP);

        gru_gates2<<<npMax * 256, 256, 0, stream>>>(
            gi, gh, hbufF, cntP + k, listP + k * 8, posC + k * 16,
            (k < 3) ? hid + lbc * NH : nullptr, pH, pL);

        gemm3_proj<<<256 * MtC, 256, 0, stream>>>(
            pH, pL, WoutH, WoutL, bout, outL, cntC + k, listC + k * 16, MtC);

        softmax_gather<<<ncMax * 64, 256, 0, stream>>>(
            outL, cntC + k, listC + k * 16, emb,
            (k < 3) ? hid + lbc * NH : nullptr, xH, xL, hH, hL, hbufF);
    }
}